// Round 8
// baseline (91.400 us; speedup 1.0000x reference)
//
#include <hip/hip_runtime.h>
#include <math.h>

#define NCOL 8192
#define NROW 4096
#define KSEL 819
#define TPB  256
#define VPT  8            // f32x4 per thread = 32 elements
#define ROWS 4            // rows per block; grid = NROW/ROWS = 1024 = 4 blocks/CU
#define NBKT 1024
#define KPIV 0xBF866666u  // f2k(1.05f): survivor pivot in key space
#define LCAP 64

typedef float f32x4 __attribute__((ext_vector_type(4)));

// Per-column boost factors, recomputed every launch (deterministic).
__device__ __align__(16) float g_boost[NCOL];

__global__ void boost_kernel(const float* __restrict__ duty) {
    int i = blockIdx.x * blockDim.x + threadIdx.x;
    if (i < NCOL) {
        // target_density = 819/8192 exactly; boost_strength = 1
        float diff = (0.0999755859375f - duty[i]);
        g_boost[i] = (float)exp((double)diff);   // correctly-rounded f32 exp (matches np)
    }
}

__device__ __forceinline__ unsigned f2k(float f) {
    unsigned u = __float_as_uint(f);
    return u ^ (0x80000000u | (unsigned)((int)u >> 31));
}
__device__ __forceinline__ int kbucket(unsigned k) {
    int b = (int)(k >> 14) - (int)(KPIV >> 14);   // survivors -> [0, 1023+] clamped
    return (b > NBKT - 1) ? (NBKT - 1) : b;
}

__global__ __launch_bounds__(TPB) void kwinners_kernel(const float* __restrict__ x,
                                                       float* __restrict__ out) {
    __shared__ __align__(16) int hist[NBKT];        // 4 KB (also fallback bins / tie list)
    __shared__ unsigned list[LCAP];
    __shared__ int wtot[4];
    __shared__ int lds_cnt, lds_sel, lds_R, lds_E;

    const int t = threadIdx.x, lane = t & 63, w = t >> 6;
    const int row0 = blockIdx.x * ROWS;
    const f32x4* b4 = (const f32x4*)g_boost;

    f32x4 xv[VPT], xp[VPT];
    {   // prologue: load first row
        const f32x4* x4 = (const f32x4*)(x + (size_t)row0 * NCOL);
#pragma unroll
        for (int j = 0; j < VPT; ++j) xv[j] = x4[t + TPB * j];
    }

    for (int r = 0; r < ROWS; ++r) {
        const int row = row0 + r;
        f32x4* o4 = (f32x4*)(out + (size_t)row * NCOL);

        // ---- phase 1: zero hist/counter; ISSUE next row's loads (in flight all select) ----
        ((int4*)hist)[t] = make_int4(0, 0, 0, 0);   // 1024 ints by 256 threads
        if (t == 0) lds_cnt = 0;
        if (r + 1 < ROWS) {
            const f32x4* xn = (const f32x4*)(x + (size_t)(row + 1) * NCOL);
#pragma unroll
            for (int j = 0; j < VPT; ++j) xp[j] = xn[t + TPB * j];
        }
        __syncthreads();

        // ---- phase 2: survivor histogram (keys from registers) ----
#pragma unroll
        for (int j = 0; j < VPT; ++j) {
            f32x4 bb = b4[t + TPB * j];
            unsigned k0 = f2k(xv[j].x * bb.x), k1 = f2k(xv[j].y * bb.y);
            unsigned k2 = f2k(xv[j].z * bb.z), k3 = f2k(xv[j].w * bb.w);
            if (k0 > KPIV) atomicAdd(&hist[kbucket(k0)], 1);
            if (k1 > KPIV) atomicAdd(&hist[kbucket(k1)], 1);
            if (k2 > KPIV) atomicAdd(&hist[kbucket(k2)], 1);
            if (k3 > KPIV) atomicAdd(&hist[kbucket(k3)], 1);
        }
        __syncthreads();

        // ---- phase 3: redundant per-wave suffix scan (no LDS roundtrip, no barrier) ----
        int arr[16];
        {
            int4 a0 = ((const int4*)hist)[4 * lane + 0];
            int4 a1 = ((const int4*)hist)[4 * lane + 1];
            int4 a2 = ((const int4*)hist)[4 * lane + 2];
            int4 a3 = ((const int4*)hist)[4 * lane + 3];
            arr[0]=a0.x; arr[1]=a0.y; arr[2]=a0.z; arr[3]=a0.w;
            arr[4]=a1.x; arr[5]=a1.y; arr[6]=a1.z; arr[7]=a1.w;
            arr[8]=a2.x; arr[9]=a2.y; arr[10]=a2.z; arr[11]=a2.w;
            arr[12]=a3.x; arr[13]=a3.y; arr[14]=a3.z; arr[15]=a3.w;
        }
        int ts = 0;
#pragma unroll
        for (int b = 0; b < 16; ++b) ts += arr[b];
        int s = ts;
#pragma unroll
        for (int off = 1; off < 64; off <<= 1) {
            int o = __shfl_down(s, off);
            if (lane + off < 64) s += o;
        }
        const int C = __shfl(s, 0);          // wave-uniform, identical across waves
        bool fb = (C < KSEL);
        unsigned th = 0; int Rf = 0, E = 0;

        if (!fb) {
            const int S_ab = s - ts;
            bool cross = (S_ab < KSEL) && (S_ab + ts >= KSEL);
            int sel_l = 0, r1_l = 0;
            if (cross) {
                int cum = S_ab;
#pragma unroll
                for (int b = 15; b >= 0; --b) {
                    int nx = cum + arr[b];
                    if (cum < KSEL && nx >= KSEL) { sel_l = 16 * lane + b; r1_l = KSEL - cum; }
                    cum = nx;
                }
            }
            unsigned long long m = __ballot(cross);
            int src = (int)__ffsll(m) - 1;
            const int sel = __shfl(sel_l, src);
            const int R1  = __shfl(r1_l, src);

            // ---- phase 4: gather selected bucket ----
#pragma unroll
            for (int j = 0; j < VPT; ++j) {
                f32x4 bb = b4[t + TPB * j];
                unsigned kk[4] = {f2k(xv[j].x*bb.x), f2k(xv[j].y*bb.y),
                                  f2k(xv[j].z*bb.z), f2k(xv[j].w*bb.w)};
#pragma unroll
                for (int c = 0; c < 4; ++c)
                    if (kk[c] > KPIV && kbucket(kk[c]) == sel) {
                        int sl = atomicAdd(&lds_cnt, 1);
                        if (sl < LCAP) list[sl] = kk[c];
                    }
            }
            __syncthreads();
            const int n = lds_cnt;
            if (n > LCAP) fb = true;
            else {
                // tiny exact select, redundant per wave (n <= 64)
                unsigned myk = (lane < n) ? list[lane] : 0u;
                int g = 0, e = 0;
                for (int i = 0; i < n; ++i) {
                    unsigned ki = __shfl(myk, i);
                    g += (ki > myk) ? 1 : 0;
                    e += (ki == myk) ? 1 : 0;
                }
                unsigned cand = (lane < n && g < R1 && g + e >= R1) ? myk : 0u;
#pragma unroll
                for (int off = 1; off < 64; off <<= 1) {
                    unsigned o = __shfl_xor(cand, off);
                    cand = (o > cand) ? o : cand;
                }
                th = cand;

                // ---- phase 5: certify + speculative write (fused) ----
                int GE = 0;
#pragma unroll
                for (int j = 0; j < VPT; ++j) {
                    f32x4 bb = b4[t + TPB * j];
                    unsigned k0 = f2k(xv[j].x*bb.x), k1 = f2k(xv[j].y*bb.y);
                    unsigned k2 = f2k(xv[j].z*bb.z), k3 = f2k(xv[j].w*bb.w);
                    GE += (k0 > th) + (k1 > th) + (k2 > th) + (k3 > th);
                    GE += ((k0 == th) + (k1 == th) + (k2 == th) + (k3 == th)) << 16;
                    f32x4 rr;
                    rr.x = (k0 >= th) ? xv[j].x : 0.0f;
                    rr.y = (k1 >= th) ? xv[j].y : 0.0f;
                    rr.z = (k2 >= th) ? xv[j].z : 0.0f;
                    rr.w = (k3 >= th) ? xv[j].w : 0.0f;
                    __builtin_nontemporal_store(rr, &o4[t + TPB * j]);
                }
#pragma unroll
                for (int off = 1; off < 64; off <<= 1) GE += __shfl_xor(GE, off);
                if (lane == 0) wtot[w] = GE;
                __syncthreads();
                const int GEt = wtot[0] + wtot[1] + wtot[2] + wtot[3];
                const int G = GEt & 0xFFFF, Eg = GEt >> 16;
                if (G < KSEL && G + Eg >= KSEL) { Rf = KSEL - G; E = Eg; }
                else fb = true;
            }
        }

        if (fb) {   // guaranteed block-wide 4x8-bit radix (rare), then rewrite row
            asm volatile("s_waitcnt vmcnt(0)" ::: "memory");
            __syncthreads();
            unsigned prefix = 0; int R = KSEL;
            for (int p = 0; p < 4; ++p) {
                const int sh = 24 - 8 * p;
                if (t < 64) ((int4*)hist)[t] = make_int4(0, 0, 0, 0);   // 256 bins
                __syncthreads();
#pragma unroll
                for (int j = 0; j < VPT; ++j) {
                    f32x4 bb = b4[t + TPB * j];
                    unsigned kk[4] = {f2k(xv[j].x*bb.x), f2k(xv[j].y*bb.y),
                                      f2k(xv[j].z*bb.z), f2k(xv[j].w*bb.w)};
#pragma unroll
                    for (int c = 0; c < 4; ++c)
                        if (p == 0 || (kk[c] >> (sh + 8)) == (prefix >> (sh + 8)))
                            atomicAdd(&hist[(kk[c] >> sh) & 255u], 1);
                }
                __syncthreads();
                int h = hist[t], s2 = h;
#pragma unroll
                for (int off = 1; off < 64; off <<= 1) {
                    int o = __shfl_down(s2, off);
                    if (lane + off < 64) s2 += o;
                }
                if (lane == 0) wtot[w] = s2;
                __syncthreads();
                int S_later = 0;
#pragma unroll
                for (int w2 = 0; w2 < 4; ++w2) if (w2 > w) S_later += wtot[w2];
                const int S_ab2 = (s2 - h) + S_later;
                if (S_ab2 < R && S_ab2 + h >= R) { lds_sel = t; lds_R = R - S_ab2; lds_E = h; }
                __syncthreads();
                prefix |= ((unsigned)lds_sel) << sh;
                R = lds_R;
            }
            th = prefix; Rf = R; E = lds_E;
#pragma unroll
            for (int j = 0; j < VPT; ++j) {
                f32x4 bb = b4[t + TPB * j];
                unsigned k0 = f2k(xv[j].x*bb.x), k1 = f2k(xv[j].y*bb.y);
                unsigned k2 = f2k(xv[j].z*bb.z), k3 = f2k(xv[j].w*bb.w);
                f32x4 rr;
                rr.x = (k0 >= th) ? xv[j].x : 0.0f;
                rr.y = (k1 >= th) ? xv[j].y : 0.0f;
                rr.z = (k2 >= th) ? xv[j].z : 0.0f;
                rr.w = (k3 >= th) ? xv[j].w : 0.0f;
                o4[t + TPB * j] = rr;
            }
            __syncthreads();
        }

        if (E > Rf) {   // tie demotion (lax.top_k keeps lowest columns) — rare
            asm volatile("s_waitcnt vmcnt(0)" ::: "memory");
            __syncthreads();
            unsigned short* tl = (unsigned short*)hist;   // cap 2048 cols
            if (t == 0) lds_cnt = 0;
            __syncthreads();
#pragma unroll
            for (int j = 0; j < VPT; ++j) {
                f32x4 bb = b4[t + TPB * j];
                unsigned kk[4] = {f2k(xv[j].x*bb.x), f2k(xv[j].y*bb.y),
                                  f2k(xv[j].z*bb.z), f2k(xv[j].w*bb.w)};
#pragma unroll
                for (int c = 0; c < 4; ++c)
                    if (kk[c] == th) {
                        int sl = atomicAdd(&lds_cnt, 1);
                        if (sl < 2048) tl[sl] = (unsigned short)(4 * (t + TPB * j) + c);
                    }
            }
            __syncthreads();
            const int ntie = lds_cnt;
            float* orow = out + (size_t)row * NCOL;
            if (ntie <= 2048) {
#pragma unroll
                for (int j = 0; j < VPT; ++j) {
                    f32x4 bb = b4[t + TPB * j];
                    unsigned kk[4] = {f2k(xv[j].x*bb.x), f2k(xv[j].y*bb.y),
                                      f2k(xv[j].z*bb.z), f2k(xv[j].w*bb.w)};
#pragma unroll
                    for (int c = 0; c < 4; ++c)
                        if (kk[c] == th) {
                            const int col = 4 * (t + TPB * j) + c;
                            int rk = 0;
                            for (int i = 0; i < ntie; ++i) rk += (tl[i] < col) ? 1 : 0;
                            if (rk >= Rf) orow[col] = 0.0f;
                        }
                }
            } else if (t == 0) {   // >2048 identical keys: never on real data, but correct
                int seen = 0;
                for (int col = 0; col < NCOL; ++col) {
                    float v = x[(size_t)row * NCOL + col] * g_boost[col];
                    if (f2k(v) == th) { if (seen >= Rf) orow[col] = 0.0f; ++seen; }
                }
            }
            __syncthreads();
        }

        if (r + 1 < ROWS) {
#pragma unroll
            for (int j = 0; j < VPT; ++j) xv[j] = xp[j];   // vmcnt wait lands here
        }
    }
}

extern "C" void kernel_launch(void* const* d_in, const int* in_sizes, int n_in,
                              void* d_out, int out_size, void* d_ws, size_t ws_size,
                              hipStream_t stream) {
    const float* x = (const float*)d_in[0];        // [4096, 8192] f32
    const float* duty = (const float*)d_in[1];     // [8192] f32
    float* out = (float*)d_out;                    // [4096, 8192] f32
    (void)in_sizes; (void)n_in; (void)out_size; (void)d_ws; (void)ws_size;

    boost_kernel<<<(NCOL + 255) / 256, 256, 0, stream>>>(duty);
    kwinners_kernel<<<NROW / ROWS, TPB, 0, stream>>>(x, out);
}

// Round 9
// 73.595 us; speedup vs baseline: 1.2419x; 1.2419x over previous
//
#include <hip/hip_runtime.h>
#include <math.h>

#define NCOL 8192
#define NROW 4096
#define KSEL 819
#define TPB  128          // 2 waves per block; one block per row
#define VPT  16           // f32x4 per thread = 64 elements
#define NBKT 1024
#define KPIV 0xBF866666u  // f2k(1.05f): survivor pivot in key space
#define LCAP 64

typedef float f32x4 __attribute__((ext_vector_type(4)));

// Per-column boost factors, recomputed every launch (deterministic).
__device__ __align__(16) float g_boost[NCOL];

__global__ void boost_kernel(const float* __restrict__ duty) {
    int i = blockIdx.x * blockDim.x + threadIdx.x;
    if (i < NCOL) {
        // target_density = 819/8192 exactly; boost_strength = 1
        float diff = (0.0999755859375f - duty[i]);
        g_boost[i] = (float)exp((double)diff);   // correctly-rounded f32 exp (matches np)
    }
}

__device__ __forceinline__ unsigned f2k(float f) {
    unsigned u = __float_as_uint(f);
    return u ^ (0x80000000u | (unsigned)((int)u >> 31));
}
__device__ __forceinline__ int kbucket(unsigned k) {
    int b = (int)(k >> 14) - (int)(KPIV >> 14);   // survivors -> [0, 1023] clamped
    return (b > NBKT - 1) ? (NBKT - 1) : b;
}

__global__ __launch_bounds__(TPB) void kwinners_kernel(const float* __restrict__ x,
                                                       float* __restrict__ out) {
    __shared__ __align__(16) int hist[NBKT];      // 4 KB; also fallback bins / tie list
    __shared__ unsigned list[LCAP];
    __shared__ int wtot[2];
    __shared__ int lds_cnt, lds_sel, lds_R, lds_E;

    const int t = threadIdx.x, lane = t & 63, w = t >> 6;
    const int row = blockIdx.x;
    const f32x4* x4 = (const f32x4*)(x + (size_t)row * NCOL);
    const f32x4* b4 = (const f32x4*)g_boost;
    f32x4* o4 = (f32x4*)(out + (size_t)row * NCOL);

    unsigned kr[VPT][4];   // 64 key registers — the only row state kept

    // zero hist (128 threads x 2 int4 = 1024 ints) + counter
    {
        const int4 z = make_int4(0, 0, 0, 0);
        ((int4*)hist)[2 * t] = z; ((int4*)hist)[2 * t + 1] = z;
        if (t == 0) lds_cnt = 0;
    }
    // load x + boost once; keys -> registers
#pragma unroll
    for (int j = 0; j < VPT; ++j) {
        f32x4 xx = x4[t + TPB * j];
        f32x4 bb = b4[t + TPB * j];
        kr[j][0] = f2k(xx.x * bb.x);
        kr[j][1] = f2k(xx.y * bb.y);
        kr[j][2] = f2k(xx.z * bb.z);
        kr[j][3] = f2k(xx.w * bb.w);
    }
    __syncthreads();                               // sync 1: zeros visible

    // survivor histogram
#pragma unroll
    for (int j = 0; j < VPT; ++j)
#pragma unroll
        for (int c = 0; c < 4; ++c) {
            unsigned k = kr[j][c];
            if (k > KPIV) atomicAdd(&hist[kbucket(k)], 1);
        }
    __syncthreads();                               // sync 2: hist complete

    // redundant per-wave suffix scan of 1024 bins (16/lane); no writeback, no sync
    int arr[16];
    {
        int4 a0 = ((const int4*)hist)[4 * lane + 0];
        int4 a1 = ((const int4*)hist)[4 * lane + 1];
        int4 a2 = ((const int4*)hist)[4 * lane + 2];
        int4 a3 = ((const int4*)hist)[4 * lane + 3];
        arr[0]=a0.x; arr[1]=a0.y; arr[2]=a0.z; arr[3]=a0.w;
        arr[4]=a1.x; arr[5]=a1.y; arr[6]=a1.z; arr[7]=a1.w;
        arr[8]=a2.x; arr[9]=a2.y; arr[10]=a2.z; arr[11]=a2.w;
        arr[12]=a3.x; arr[13]=a3.y; arr[14]=a3.z; arr[15]=a3.w;
    }
    int ts = 0;
#pragma unroll
    for (int b = 0; b < 16; ++b) ts += arr[b];
    int s = ts;
#pragma unroll
    for (int off = 1; off < 64; off <<= 1) {
        int o = __shfl_down(s, off);
        if (lane + off < 64) s += o;
    }
    const int C = __shfl(s, 0);                    // wave-uniform survivor total

    unsigned th = 0; int Rf = 0, E = 0;
    bool fb = (C < KSEL);

    if (!fb) {
        const int S_ab = s - ts;
        bool cross = (S_ab < KSEL) && (S_ab + ts >= KSEL);
        int sel_l = 0, r1_l = 0;
        if (cross) {
            int cum = S_ab;
#pragma unroll
            for (int b = 15; b >= 0; --b) {
                int nx = cum + arr[b];
                if (cum < KSEL && nx >= KSEL) { sel_l = 16 * lane + b; r1_l = KSEL - cum; }
                cum = nx;
            }
        }
        unsigned long long m = __ballot(cross);    // exactly one lane per wave
        int src = (int)__ffsll(m) - 1;
        const int sel = __shfl(sel_l, src);
        const int R1  = __shfl(r1_l, src);

        // gather selected bucket's keys
#pragma unroll
        for (int j = 0; j < VPT; ++j)
#pragma unroll
            for (int c = 0; c < 4; ++c) {
                unsigned k = kr[j][c];
                if (k > KPIV && kbucket(k) == sel) {
                    int sl = atomicAdd(&lds_cnt, 1);
                    if (sl < LCAP) list[sl] = k;
                }
            }
        __syncthreads();                           // sync 3: list complete
        const int n = lds_cnt;
        if (n > LCAP) fb = true;
        else {
            // redundant per-wave exact select on the tiny list (n <= 64)
            unsigned myk = (lane < n) ? list[lane] : 0u;
            int g = 0, e = 0;
            for (int i = 0; i < n; ++i) {
                unsigned ki = __shfl(myk, i);
                g += (ki > myk) ? 1 : 0;
                e += (ki == myk) ? 1 : 0;
            }
            unsigned cand = (lane < n && g < R1 && g + e >= R1) ? myk : 0u;
#pragma unroll
            for (int off = 1; off < 64; off <<= 1) {
                unsigned o = __shfl_xor(cand, off);
                cand = (o > cand) ? o : cand;
            }
            th = cand;

            // certify + speculative write, fused (x reloaded — L2/L3-hot)
            int GE = 0;
#pragma unroll
            for (int j = 0; j < VPT; ++j) {
                f32x4 xx = x4[t + TPB * j];
                unsigned k0 = kr[j][0], k1 = kr[j][1], k2 = kr[j][2], k3 = kr[j][3];
                GE += (k0 > th) + (k1 > th) + (k2 > th) + (k3 > th);
                GE += ((k0 == th) + (k1 == th) + (k2 == th) + (k3 == th)) << 16;
                f32x4 rr;
                rr.x = (k0 >= th) ? xx.x : 0.0f;
                rr.y = (k1 >= th) ? xx.y : 0.0f;
                rr.z = (k2 >= th) ? xx.z : 0.0f;
                rr.w = (k3 >= th) ? xx.w : 0.0f;
                __builtin_nontemporal_store(rr, &o4[t + TPB * j]);
            }
#pragma unroll
            for (int off = 1; off < 64; off <<= 1) GE += __shfl_xor(GE, off);
            if (lane == 0) wtot[w] = GE;
            __syncthreads();                       // sync 4: combine both waves
            const int GEt = wtot[0] + wtot[1];
            const int G = GEt & 0xFFFF, Eg = GEt >> 16;
            if (G < KSEL && G + Eg >= KSEL) { Rf = KSEL - G; E = Eg; }
            else fb = true;                        // certification failed
        }
    }

    if (fb) {   // guaranteed 4x8-bit key radix select (rare), then rewrite row
        asm volatile("s_waitcnt vmcnt(0)" ::: "memory");
        __syncthreads();
        unsigned prefix = 0; int R = KSEL;
        for (int p = 0; p < 4; ++p) {
            const int sh = 24 - 8 * p;
            if (t < 64) ((int4*)hist)[t] = make_int4(0, 0, 0, 0);   // 256 bins
            __syncthreads();
#pragma unroll
            for (int j = 0; j < VPT; ++j)
#pragma unroll
                for (int c = 0; c < 4; ++c) {
                    unsigned k = kr[j][c];
                    if (p == 0 || (k >> (sh + 8)) == (prefix >> (sh + 8)))
                        atomicAdd(&hist[(k >> sh) & 255u], 1);
                }
            __syncthreads();
            const int b0 = hist[2 * t], b1 = hist[2 * t + 1];
            int ts2 = b0 + b1, s2 = ts2;
#pragma unroll
            for (int off = 1; off < 64; off <<= 1) {
                int o = __shfl_down(s2, off);
                if (lane + off < 64) s2 += o;
            }
            if (lane == 0) wtot[w] = s2;           // wave totals
            __syncthreads();
            const int S_later = (w == 0) ? wtot[1] : 0;
            const int S_ab2 = (s2 - ts2) + S_later;
            if (S_ab2 < R && S_ab2 + ts2 >= R) {
                int cum = S_ab2;
                int nx = cum + b1;
                if (cum < R && nx >= R) { lds_sel = 2 * t + 1; lds_R = R - cum; lds_E = b1; }
                cum = nx; nx = cum + b0;
                if (cum < R && nx >= R) { lds_sel = 2 * t;     lds_R = R - cum; lds_E = b0; }
            }
            __syncthreads();
            prefix |= ((unsigned)lds_sel) << sh;
            R = lds_R;
        }
        th = prefix; Rf = R; E = lds_E;
#pragma unroll
        for (int j = 0; j < VPT; ++j) {
            f32x4 xx = x4[t + TPB * j];
            f32x4 rr;
            rr.x = (kr[j][0] >= th) ? xx.x : 0.0f;
            rr.y = (kr[j][1] >= th) ? xx.y : 0.0f;
            rr.z = (kr[j][2] >= th) ? xx.z : 0.0f;
            rr.w = (kr[j][3] >= th) ? xx.w : 0.0f;
            o4[t + TPB * j] = rr;
        }
    }

    if (E > Rf) {   // tie demotion (lax.top_k keeps lowest columns) — rare
        asm volatile("s_waitcnt vmcnt(0)" ::: "memory");
        __syncthreads();
        unsigned short* tl = (unsigned short*)hist;   // 4 KB -> cap 2048 cols
        if (t == 0) lds_cnt = 0;
        __syncthreads();
#pragma unroll
        for (int j = 0; j < VPT; ++j)
#pragma unroll
            for (int c = 0; c < 4; ++c)
                if (kr[j][c] == th) {
                    int sl = atomicAdd(&lds_cnt, 1);
                    if (sl < 2048) tl[sl] = (unsigned short)(4 * (t + TPB * j) + c);
                }
        __syncthreads();
        const int ntie = lds_cnt;
        float* orow = out + (size_t)row * NCOL;
        if (ntie <= 2048) {
#pragma unroll
            for (int j = 0; j < VPT; ++j)
#pragma unroll
                for (int c = 0; c < 4; ++c)
                    if (kr[j][c] == th) {
                        const int col = 4 * (t + TPB * j) + c;
                        int rk = 0;
                        for (int i = 0; i < ntie; ++i) rk += (tl[i] < col) ? 1 : 0;
                        if (rk >= Rf) orow[col] = 0.0f;
                    }
        } else if (t == 0) {   // >2048 identical keys: never on real data, but correct
            int seen = 0;
            for (int col = 0; col < NCOL; ++col) {
                float v = x[(size_t)row * NCOL + col] * g_boost[col];
                if (f2k(v) == th) { if (seen >= Rf) orow[col] = 0.0f; ++seen; }
            }
        }
    }
}

extern "C" void kernel_launch(void* const* d_in, const int* in_sizes, int n_in,
                              void* d_out, int out_size, void* d_ws, size_t ws_size,
                              hipStream_t stream) {
    const float* x = (const float*)d_in[0];        // [4096, 8192] f32
    const float* duty = (const float*)d_in[1];     // [8192] f32
    float* out = (float*)d_out;                    // [4096, 8192] f32
    (void)in_sizes; (void)n_in; (void)out_size; (void)d_ws; (void)ws_size;

    boost_kernel<<<(NCOL + 255) / 256, 256, 0, stream>>>(duty);
    kwinners_kernel<<<NROW, TPB, 0, stream>>>(x, out);
}